// Round 1
// baseline (382.869 us; speedup 1.0000x reference)
//
#include <hip/hip_runtime.h>
#include <stdint.h>
#include <stddef.h>

// Match numpy float32 rounding: forbid fma contraction in all float math below.
#pragma clang fp contract(off)

#define N8   819200u
#define N16  204800u
#define N32  51200u
#define NTOT 1075200u
#define TOPK 2048
#define CAND_MAX 8192
#define NBIN 131072u
#define NMS_THR 0.4f
#define DET_THR 0.5f

// ws byte offsets
#define OFF_HIST  0u          // u32[131072]  512KB
#define OFF_META  524288u     // u32[16]      meta[0]=cut, meta[2]=total, meta[3]=cand_count
#define OFF_CAND  524352u     // u64[8192]    64KB
#define OFF_TIDX  589888u     // u32[2048]
#define OFF_TCONF 598080u     // f32[2048]
#define OFF_BOX   606272u     // f32[2048*4]  (16B aligned)
#define OFF_SUPP  639040u     // u64[2048*32] 512KB

__device__ __forceinline__ float load_conf(unsigned a, const float* __restrict__ s8,
                                           const float* __restrict__ s16,
                                           const float* __restrict__ s32) {
  if (a < N8) return s8[a];
  if (a < N8 + N16) return s16[a - N8];
  return s32[a - (N8 + N16)];
}

__device__ __forceinline__ void decode(unsigned a,
    const float* __restrict__ b8, const float* __restrict__ l8,
    const float* __restrict__ b16, const float* __restrict__ l16,
    const float* __restrict__ b32, const float* __restrict__ l32,
    float& cx, float& cy, float& s, const float*& bb, const float*& lm) {
  if (a < N8) {
    unsigned cell = a >> 1;
    cx = (float)((cell % 640u) * 8u); cy = (float)((cell / 640u) * 8u);
    s = 8.f; bb = b8 + (size_t)a * 4; lm = l8 + (size_t)a * 10;
  } else if (a < N8 + N16) {
    unsigned loc = a - N8; unsigned cell = loc >> 1;
    cx = (float)((cell % 320u) * 16u); cy = (float)((cell / 320u) * 16u);
    s = 16.f; bb = b16 + (size_t)loc * 4; lm = l16 + (size_t)loc * 10;
  } else {
    unsigned loc = a - (N8 + N16); unsigned cell = loc >> 1;
    cx = (float)((cell % 160u) * 32u); cy = (float)((cell / 160u) * 32u);
    s = 32.f; bb = b32 + (size_t)loc * 4; lm = l32 + (size_t)loc * 10;
  }
}

// K1: histogram of conf>=0.5 on 17-bit prefix of (bits - bits(0.5))
__global__ void k_hist(const float* __restrict__ s8, const float* __restrict__ s16,
                       const float* __restrict__ s32, unsigned* __restrict__ hist) {
  unsigned i = blockIdx.x * blockDim.x + threadIdx.x;
  unsigned st = gridDim.x * blockDim.x;
  for (unsigned a = i; a < NTOT; a += st) {
    float c = load_conf(a, s8, s16, s32);
    if (c >= DET_THR) {
      unsigned v = (__float_as_uint(c) - 0x3F000000u) >> 8;
      if (v > NBIN - 1u) v = NBIN - 1u;
      atomicAdd(&hist[v], 1u);
    }
  }
}

// K2: find cutoff prefix (smallest p with suffix-count >= TOPK); single WG
__global__ void __launch_bounds__(1024) k_scan(const unsigned* __restrict__ hist,
                                               unsigned* __restrict__ meta) {
  __shared__ unsigned suf[1024];
  int t = threadIdx.x;
  const unsigned* hp = hist + (size_t)t * 128;
  unsigned s = 0;
  for (int b = 0; b < 128; b++) s += hp[b];
  suf[t] = s;
  __syncthreads();
  for (int d = 1; d < 1024; d <<= 1) {
    unsigned v = (t + d < 1024) ? suf[t + d] : 0u;
    __syncthreads();
    suf[t] += v;
    __syncthreads();
  }
  unsigned total = suf[0];
  unsigned mine = suf[t];
  unsigned nxt = (t < 1023) ? suf[t + 1] : 0u;
  if (total < (unsigned)TOPK) {
    if (t == 0) { meta[0] = 0u; meta[2] = total; }
    return;
  }
  if (mine >= (unsigned)TOPK && nxt < (unsigned)TOPK) {
    unsigned run = nxt, cut = (unsigned)t * 128u;
    for (int b = 127; b >= 0; b--) {
      run += hp[b];
      if (run >= (unsigned)TOPK) { cut = (unsigned)t * 128u + (unsigned)b; break; }
    }
    meta[0] = cut; meta[2] = total;
  }
}

// K3: compact candidates (>= cutoff prefix) as 64-bit sort keys
__global__ void k_compact(const float* __restrict__ s8, const float* __restrict__ s16,
                          const float* __restrict__ s32, unsigned* __restrict__ meta,
                          unsigned long long* __restrict__ cand) {
  unsigned cut = meta[0];
  unsigned i = blockIdx.x * blockDim.x + threadIdx.x;
  unsigned st = gridDim.x * blockDim.x;
  for (unsigned a = i; a < NTOT; a += st) {
    float c = load_conf(a, s8, s16, s32);
    if (c >= DET_THR) {
      unsigned b = __float_as_uint(c);
      unsigned v = (b - 0x3F000000u) >> 8;
      if (v >= cut) {
        unsigned pos = atomicAdd(&meta[3], 1u);
        if (pos < (unsigned)CAND_MAX)
          cand[pos] = ((unsigned long long)b << 32) |
                      (unsigned long long)(0xFFFFFFFFu - a);
      }
    }
  }
}

// K4: bitonic sort candidates descending (key = conf bits, tie -> lower index),
//     emit top-2048 idx/conf and decoded boxes.
__global__ void __launch_bounds__(1024) k_sort_gather(
    const unsigned long long* __restrict__ cand, const unsigned* __restrict__ meta,
    const float* __restrict__ b8, const float* __restrict__ l8,
    const float* __restrict__ b16, const float* __restrict__ l16,
    const float* __restrict__ b32, const float* __restrict__ l32,
    const float* __restrict__ dsp,
    unsigned* __restrict__ tidx, float* __restrict__ tconf, float* __restrict__ box) {
  __shared__ unsigned long long sk[CAND_MAX];
  unsigned count = meta[3];
  if (count > (unsigned)CAND_MAX) count = (unsigned)CAND_MAX;
  int P = (count <= 2048u) ? 2048 : (count <= 4096u ? 4096 : 8192);
  for (int i = threadIdx.x; i < P; i += 1024) sk[i] = (i < (int)count) ? cand[i] : 0ull;
  __syncthreads();
  for (int k = 2; k <= P; k <<= 1) {
    for (int j = k >> 1; j > 0; j >>= 1) {
      for (int i = threadIdx.x; i < P; i += 1024) {
        int ixj = i ^ j;
        if (ixj > i) {
          unsigned long long a = sk[i], b = sk[ixj];
          bool up = ((i & k) == 0);
          if (up ? (a < b) : (a > b)) { sk[i] = b; sk[ixj] = a; }
        }
      }
      __syncthreads();
    }
  }
  float ds = dsp[0];
  for (int r = threadIdx.x; r < TOPK; r += 1024) {
    unsigned long long e = sk[r];
    float conf = __uint_as_float((unsigned)(e >> 32));
    bool val = (r < (int)count) && (conf >= DET_THR);
    if (val) {
      unsigned a = 0xFFFFFFFFu - (unsigned)(e & 0xFFFFFFFFull);
      float cx, cy, s; const float* bb; const float* lm;
      decode(a, b8, l8, b16, l16, b32, l32, cx, cy, s, bb, lm);
      float b0 = bb[0] * s, b1 = bb[1] * s, b2 = bb[2] * s, b3 = bb[3] * s;
      box[r * 4 + 0] = (cx - b0) / ds;
      box[r * 4 + 1] = (cy - b1) / ds;
      box[r * 4 + 2] = (cx + b2) / ds;
      box[r * 4 + 3] = (cy + b3) / ds;
      tidx[r] = a; tconf[r] = conf;
    } else {
      tidx[r] = 0xFFFFFFFFu; tconf[r] = -1.0f;
      box[r * 4 + 0] = 0.f; box[r * 4 + 1] = 0.f;
      box[r * 4 + 2] = 0.f; box[r * 4 + 3] = 0.f;
    }
  }
}

// K5: bit-packed suppression matrix: bit[i][j] = (iou > thr) && (j > i)
__global__ void __launch_bounds__(256) k_supp(const float* __restrict__ box,
                                              unsigned long long* __restrict__ supp) {
  int i = blockIdx.x;
  const float4 bi = ((const float4*)box)[i];
  float ai = fmaxf(bi.z - bi.x, 0.f) * fmaxf(bi.w - bi.y, 0.f);
  int tid = threadIdx.x;
  int lane = tid & 63, wv = tid >> 6;
  for (int base = 0; base < TOPK; base += 256) {
    int j = base + tid;
    const float4 bj = ((const float4*)box)[j];
    float aj = fmaxf(bj.z - bj.x, 0.f) * fmaxf(bj.w - bj.y, 0.f);
    float ltx = fmaxf(bi.x, bj.x), lty = fmaxf(bi.y, bj.y);
    float rbx = fminf(bi.z, bj.z), rby = fminf(bi.w, bj.w);
    float w = fmaxf(rbx - ltx, 0.f), h = fmaxf(rby - lty, 0.f);
    float inter = w * h;
    float iou = inter / (ai + aj - inter + 1e-9f);
    bool pred = (iou > NMS_THR) && (j > i);
    unsigned long long word = __ballot(pred);
    if (lane == 0) supp[(size_t)i * 32 + (base >> 6) + wv] = word;
  }
}

// K6: sequential greedy NMS (keep mask in registers, lane l<32 owns word l),
//     then decode + write all 2048x15 outputs.
__global__ void __launch_bounds__(64) k_nms_out(
    const unsigned long long* __restrict__ supp,
    const unsigned* __restrict__ tidx, const float* __restrict__ tconf,
    const float* __restrict__ b8, const float* __restrict__ l8,
    const float* __restrict__ b16, const float* __restrict__ l16,
    const float* __restrict__ b32, const float* __restrict__ l32,
    const float* __restrict__ dsp, float* __restrict__ out) {
  int lane = threadIdx.x;
  __shared__ unsigned long long keepw[32];
  // valid mask = conf >= 0.5 (keep init)
  unsigned long long keepreg = 0ull;
  for (int w = 0; w < 32; w++) {
    unsigned long long m = __ballot(tconf[w * 64 + lane] >= DET_THR);
    if (lane == w) keepreg = m;
  }
  const unsigned long long* sp = supp + lane;
  bool ld = lane < 32;
  unsigned long long buf0 = ld ? sp[0 * 32] : 0ull;
  unsigned long long buf1 = ld ? sp[1 * 32] : 0ull;
  unsigned long long buf2 = ld ? sp[2 * 32] : 0ull;
  unsigned long long buf3 = ld ? sp[3 * 32] : 0ull;
#define NMS_STEP(U, B)                                                        \
  {                                                                           \
    unsigned long long row = B;                                               \
    if (ld && (i + U + 4) < TOPK) B = sp[(size_t)(i + U + 4) * 32];           \
    unsigned long long kw = __shfl(keepreg, (i + U) >> 6);                    \
    if ((kw >> ((i + U) & 63)) & 1ull) keepreg &= ~row;                       \
  }
  for (int i = 0; i < TOPK; i += 4) {
    NMS_STEP(0, buf0)
    NMS_STEP(1, buf1)
    NMS_STEP(2, buf2)
    NMS_STEP(3, buf3)
  }
#undef NMS_STEP
  if (ld) keepw[lane] = keepreg;
  __syncthreads();
  float ds = dsp[0];
  for (int rb = 0; rb < TOPK; rb += 64) {
    int r = rb + lane;
    bool kept = (keepw[r >> 6] >> (r & 63)) & 1ull;
    float o[15];
    if (kept) {
      unsigned a = tidx[r];
      float cx, cy, s; const float* bb; const float* lm;
      decode(a, b8, l8, b16, l16, b32, l32, cx, cy, s, bb, lm);
      o[0] = tconf[r];
      float b0 = bb[0] * s, b1 = bb[1] * s, b2 = bb[2] * s, b3 = bb[3] * s;
      o[1] = (cx - b0) / ds;
      o[2] = (cy - b1) / ds;
      o[3] = (cx + b2) / ds;
      o[4] = (cy + b3) / ds;
      for (int p = 0; p < 5; p++) {
        float lx = lm[2 * p] * s, ly = lm[2 * p + 1] * s;
        o[5 + 2 * p] = (cx + lx) / ds;
        o[6 + 2 * p] = (cy + ly) / ds;
      }
    } else {
      for (int c = 0; c < 15; c++) o[c] = 0.f;
    }
    for (int c = 0; c < 15; c++) out[(size_t)r * 15 + c] = o[c];
  }
}

extern "C" void kernel_launch(void* const* d_in, const int* in_sizes, int n_in,
                              void* d_out, int out_size, void* d_ws, size_t ws_size,
                              hipStream_t stream) {
  const float* s8  = (const float*)d_in[0];
  const float* b8  = (const float*)d_in[1];
  const float* l8  = (const float*)d_in[2];
  const float* s16 = (const float*)d_in[3];
  const float* b16 = (const float*)d_in[4];
  const float* l16 = (const float*)d_in[5];
  const float* s32 = (const float*)d_in[6];
  const float* b32 = (const float*)d_in[7];
  const float* l32 = (const float*)d_in[8];
  const float* dsp = (const float*)d_in[9];
  char* ws = (char*)d_ws;
  unsigned* hist = (unsigned*)(ws + OFF_HIST);
  unsigned* meta = (unsigned*)(ws + OFF_META);
  unsigned long long* cand = (unsigned long long*)(ws + OFF_CAND);
  unsigned* tidx = (unsigned*)(ws + OFF_TIDX);
  float* tconf = (float*)(ws + OFF_TCONF);
  float* box = (float*)(ws + OFF_BOX);
  unsigned long long* supp = (unsigned long long*)(ws + OFF_SUPP);
  float* out = (float*)d_out;

  hipMemsetAsync(ws, 0, OFF_META + 64, stream);  // hist + meta
  k_hist<<<2048, 256, 0, stream>>>(s8, s16, s32, hist);
  k_scan<<<1, 1024, 0, stream>>>(hist, meta);
  k_compact<<<2048, 256, 0, stream>>>(s8, s16, s32, meta, cand);
  k_sort_gather<<<1, 1024, 0, stream>>>(cand, meta, b8, l8, b16, l16, b32, l32,
                                        dsp, tidx, tconf, box);
  k_supp<<<TOPK, 256, 0, stream>>>(box, supp);
  k_nms_out<<<1, 64, 0, stream>>>(supp, tidx, tconf, b8, l8, b16, l16, b32, l32,
                                  dsp, out);
}

// Round 2
// 175.041 us; speedup vs baseline: 2.1873x; 2.1873x over previous
//
#include <hip/hip_runtime.h>
#include <stdint.h>
#include <stddef.h>

// Match numpy float32 rounding: forbid fma contraction in all float math below.
#pragma clang fp contract(off)

#define N8   819200u
#define N16  204800u
#define N32  51200u
#define NTOT 1075200u
#define TOPK 2048
#define CAND_MAX 8192
#define NBIN 16384u
#define BINSHIFT 9
#define NMS_THR 0.4f
#define DET_THR 0.5f

// ws byte offsets
#define OFF_HIST   0u        // u32[16384]   64KB
#define OFF_META   65536u    // u32[16]
#define OFF_CAND   65600u    // u64[8192]    64KB
#define OFF_TIDX   131136u   // u32[2048]
#define OFF_TCONF  139328u   // f32[2048]
#define OFF_BOX    147520u   // f32[2048*4] (16B aligned)
#define OFF_VMASK  180288u   // u32[64]
#define OFF_KEEP   180544u   // u32[64]
#define OFF_SUPP   180800u   // u64[2048*32] 512KB

__device__ __forceinline__ float load_conf(unsigned a, const float* __restrict__ s8,
                                           const float* __restrict__ s16,
                                           const float* __restrict__ s32) {
  if (a < N8) return s8[a];
  if (a < N8 + N16) return s16[a - N8];
  return s32[a - (N8 + N16)];
}

__device__ __forceinline__ void decode(unsigned a,
    const float* __restrict__ b8, const float* __restrict__ l8,
    const float* __restrict__ b16, const float* __restrict__ l16,
    const float* __restrict__ b32, const float* __restrict__ l32,
    float& cx, float& cy, float& s, const float*& bb, const float*& lm) {
  if (a < N8) {
    unsigned cell = a >> 1;
    cx = (float)((cell % 640u) * 8u); cy = (float)((cell / 640u) * 8u);
    s = 8.f; bb = b8 + (size_t)a * 4; lm = l8 + (size_t)a * 10;
  } else if (a < N8 + N16) {
    unsigned loc = a - N8; unsigned cell = loc >> 1;
    cx = (float)((cell % 320u) * 16u); cy = (float)((cell / 320u) * 16u);
    s = 16.f; bb = b16 + (size_t)loc * 4; lm = l16 + (size_t)loc * 10;
  } else {
    unsigned loc = a - (N8 + N16); unsigned cell = loc >> 1;
    cx = (float)((cell % 160u) * 32u); cy = (float)((cell / 160u) * 32u);
    s = 32.f; bb = b32 + (size_t)loc * 4; lm = l32 + (size_t)loc * 10;
  }
}

// K1: histogram of conf>=0.5 on 14-bit prefix of (bits - bits(0.5))
__global__ void k_hist(const float* __restrict__ s8, const float* __restrict__ s16,
                       const float* __restrict__ s32, unsigned* __restrict__ hist) {
  unsigned i = blockIdx.x * blockDim.x + threadIdx.x;
  unsigned st = gridDim.x * blockDim.x;
  for (unsigned a = i; a < NTOT; a += st) {
    float c = load_conf(a, s8, s16, s32);
    if (c >= DET_THR) {
      unsigned v = (__float_as_uint(c) - 0x3F000000u) >> BINSHIFT;
      if (v > NBIN - 1u) v = NBIN - 1u;
      atomicAdd(&hist[v], 1u);
    }
  }
}

// K2: find cutoff prefix (smallest p with suffix-count >= TOPK); single WG
__global__ void __launch_bounds__(1024) k_scan(const unsigned* __restrict__ hist,
                                               unsigned* __restrict__ meta) {
  __shared__ unsigned suf[1024];
  int t = threadIdx.x;
  const unsigned* hp = hist + (size_t)t * 16;
  unsigned s = 0;
  for (int b = 0; b < 16; b++) s += hp[b];
  suf[t] = s;
  __syncthreads();
  for (int d = 1; d < 1024; d <<= 1) {
    unsigned v = (t + d < 1024) ? suf[t + d] : 0u;
    __syncthreads();
    suf[t] += v;
    __syncthreads();
  }
  unsigned total = suf[0];
  unsigned mine = suf[t];
  unsigned nxt = (t < 1023) ? suf[t + 1] : 0u;
  if (total < (unsigned)TOPK) {
    if (t == 0) { meta[0] = 0u; meta[2] = total; }
    return;
  }
  if (mine >= (unsigned)TOPK && nxt < (unsigned)TOPK) {
    unsigned run = nxt, cut = (unsigned)t * 16u;
    for (int b = 15; b >= 0; b--) {
      run += hp[b];
      if (run >= (unsigned)TOPK) { cut = (unsigned)t * 16u + (unsigned)b; break; }
    }
    meta[0] = cut; meta[2] = total;
  }
}

// K3: compact candidates (>= cutoff prefix) as 64-bit sort keys
__global__ void k_compact(const float* __restrict__ s8, const float* __restrict__ s16,
                          const float* __restrict__ s32, unsigned* __restrict__ meta,
                          unsigned long long* __restrict__ cand) {
  unsigned cut = meta[0];
  unsigned i = blockIdx.x * blockDim.x + threadIdx.x;
  unsigned st = gridDim.x * blockDim.x;
  for (unsigned a = i; a < NTOT; a += st) {
    float c = load_conf(a, s8, s16, s32);
    if (c >= DET_THR) {
      unsigned b = __float_as_uint(c);
      unsigned v = (b - 0x3F000000u) >> BINSHIFT;
      if (v >= cut) {
        unsigned pos = atomicAdd(&meta[3], 1u);
        if (pos < (unsigned)CAND_MAX)
          cand[pos] = ((unsigned long long)b << 32) |
                      (unsigned long long)(0xFFFFFFFFu - a);
      }
    }
  }
}

// K4: bitonic sort candidates descending (key = conf bits, tie -> lower index),
//     emit top-2048 idx/conf, decoded boxes, and the valid bitmask.
__global__ void __launch_bounds__(1024) k_sort_gather(
    const unsigned long long* __restrict__ cand, const unsigned* __restrict__ meta,
    const float* __restrict__ b8, const float* __restrict__ l8,
    const float* __restrict__ b16, const float* __restrict__ l16,
    const float* __restrict__ b32, const float* __restrict__ l32,
    const float* __restrict__ dsp,
    unsigned* __restrict__ tidx, float* __restrict__ tconf, float* __restrict__ box,
    unsigned long long* __restrict__ vmask) {
  __shared__ unsigned long long sk[CAND_MAX];
  unsigned count = meta[3];
  if (count > (unsigned)CAND_MAX) count = (unsigned)CAND_MAX;
  int P = (count <= 2048u) ? 2048 : (count <= 4096u ? 4096 : 8192);
  for (int i = threadIdx.x; i < P; i += 1024) sk[i] = (i < (int)count) ? cand[i] : 0ull;
  __syncthreads();
  for (int k = 2; k <= P; k <<= 1) {
    for (int j = k >> 1; j > 0; j >>= 1) {
      for (int i = threadIdx.x; i < P; i += 1024) {
        int ixj = i ^ j;
        if (ixj > i) {
          unsigned long long a = sk[i], b = sk[ixj];
          bool up = ((i & k) == 0);
          if (up ? (a < b) : (a > b)) { sk[i] = b; sk[ixj] = a; }
        }
      }
      __syncthreads();
    }
  }
  float ds = dsp[0];
  for (int r = threadIdx.x; r < TOPK; r += 1024) {
    unsigned long long e = sk[r];
    float conf = __uint_as_float((unsigned)(e >> 32));
    bool val = (r < (int)count) && (conf >= DET_THR);
    if (val) {
      unsigned a = 0xFFFFFFFFu - (unsigned)(e & 0xFFFFFFFFull);
      float cx, cy, s; const float* bb; const float* lm;
      decode(a, b8, l8, b16, l16, b32, l32, cx, cy, s, bb, lm);
      float b0 = bb[0] * s, b1 = bb[1] * s, b2 = bb[2] * s, b3 = bb[3] * s;
      box[r * 4 + 0] = (cx - b0) / ds;
      box[r * 4 + 1] = (cy - b1) / ds;
      box[r * 4 + 2] = (cx + b2) / ds;
      box[r * 4 + 3] = (cy + b3) / ds;
      tidx[r] = a; tconf[r] = conf;
    } else {
      tidx[r] = 0xFFFFFFFFu; tconf[r] = -1.0f;
      box[r * 4 + 0] = 0.f; box[r * 4 + 1] = 0.f;
      box[r * 4 + 2] = 0.f; box[r * 4 + 3] = 0.f;
    }
    unsigned long long vb = __ballot(val);
    if ((threadIdx.x & 63) == 0) vmask[r >> 6] = vb;
  }
}

// K5: bit-packed suppression matrix: bit[i][j] = (iou > thr) && (j > i)
__global__ void __launch_bounds__(256) k_supp(const float* __restrict__ box,
                                              unsigned long long* __restrict__ supp) {
  int i = blockIdx.x;
  const float4 bi = ((const float4*)box)[i];
  float ai = fmaxf(bi.z - bi.x, 0.f) * fmaxf(bi.w - bi.y, 0.f);
  int tid = threadIdx.x;
  int lane = tid & 63, wv = tid >> 6;
  for (int base = 0; base < TOPK; base += 256) {
    int j = base + tid;
    const float4 bj = ((const float4*)box)[j];
    float aj = fmaxf(bj.z - bj.x, 0.f) * fmaxf(bj.w - bj.y, 0.f);
    float ltx = fmaxf(bi.x, bj.x), lty = fmaxf(bi.y, bj.y);
    float rbx = fminf(bi.z, bj.z), rby = fminf(bi.w, bj.w);
    float w = fmaxf(rbx - ltx, 0.f), h = fmaxf(rby - lty, 0.f);
    float inter = w * h;
    float iou = inter / (ai + aj - inter + 1e-9f);
    bool pred = (iou > NMS_THR) && (j > i);
    unsigned long long word = __ballot(pred);
    if (lane == 0) supp[(size_t)i * 32 + (base >> 6) + wv] = word;
  }
}

// K6: greedy NMS via chunked closure + bulk apply.
// Keep mask: lane l owns u32 word covering j in [32l, 32l+32).
// Chunk c (i in [32c,32c+32)): lane l loads T[k]=supp32[(32c+k)*64+l]; the
// diagonal 32x32 block is exactly lane c's T[], so the sequential closure runs
// branchless in lane c's registers; one readlane broadcasts the final keep
// word; then all lanes bulk-apply kw &= ~OR(T[k] for kept k).
__global__ void __launch_bounds__(64) k_nms(const unsigned* __restrict__ supp32,
                                            const unsigned* __restrict__ vmask,
                                            unsigned* __restrict__ keepmask) {
  int lane = threadIdx.x;
  unsigned kw = vmask[lane];
  const unsigned* sp = supp32 + lane;
  unsigned Ta[32], Tb[32];
#define LOADT(BUF, C)                                                         \
  _Pragma("unroll") for (int k = 0; k < 32; k++)                              \
      BUF[k] = sp[((size_t)((C) * 32 + k)) * 64];
#define PROCESS(BUF, C)                                                       \
  {                                                                           \
    unsigned w = __builtin_amdgcn_readlane(kw, (C));                          \
    _Pragma("unroll") for (int k = 0; k < 32; k++) {                          \
      unsigned mk = 0u - ((w >> k) & 1u);                                     \
      w &= ~(BUF[k] & mk);                                                    \
    }                                                                         \
    w = __builtin_amdgcn_readlane(w, (C));                                    \
    unsigned acc = 0u;                                                        \
    _Pragma("unroll") for (int k = 0; k < 32; k++) {                          \
      unsigned mk = 0u - ((w >> k) & 1u);                                     \
      acc |= BUF[k] & mk;                                                     \
    }                                                                         \
    kw &= ~acc;                                                               \
  }
  LOADT(Ta, 0)
#pragma unroll 1
  for (int c = 0; c < 64; c += 2) {
    LOADT(Tb, c + 1)
    PROCESS(Ta, c)
    if (c + 2 < 64) LOADT(Ta, c + 2)
    PROCESS(Tb, c + 1)
  }
#undef LOADT
#undef PROCESS
  keepmask[lane] = kw;
}

// K7: decode + write all 2048x15 outputs (suppressed rows zeroed)
__global__ void __launch_bounds__(256) k_out(
    const unsigned* __restrict__ keepmask,
    const unsigned* __restrict__ tidx, const float* __restrict__ tconf,
    const float* __restrict__ b8, const float* __restrict__ l8,
    const float* __restrict__ b16, const float* __restrict__ l16,
    const float* __restrict__ b32, const float* __restrict__ l32,
    const float* __restrict__ dsp, float* __restrict__ out) {
  int r = blockIdx.x * 256 + threadIdx.x;
  if (r >= TOPK) return;
  bool kept = (keepmask[r >> 5] >> (r & 31)) & 1u;
  float o[15];
  if (kept) {
    unsigned a = tidx[r];
    float cx, cy, s; const float* bb; const float* lm;
    decode(a, b8, l8, b16, l16, b32, l32, cx, cy, s, bb, lm);
    float ds = dsp[0];
    o[0] = tconf[r];
    float b0 = bb[0] * s, b1 = bb[1] * s, b2 = bb[2] * s, b3 = bb[3] * s;
    o[1] = (cx - b0) / ds;
    o[2] = (cy - b1) / ds;
    o[3] = (cx + b2) / ds;
    o[4] = (cy + b3) / ds;
    for (int p = 0; p < 5; p++) {
      float lx = lm[2 * p] * s, ly = lm[2 * p + 1] * s;
      o[5 + 2 * p] = (cx + lx) / ds;
      o[6 + 2 * p] = (cy + ly) / ds;
    }
  } else {
    for (int c = 0; c < 15; c++) o[c] = 0.f;
  }
  for (int c = 0; c < 15; c++) out[(size_t)r * 15 + c] = o[c];
}

extern "C" void kernel_launch(void* const* d_in, const int* in_sizes, int n_in,
                              void* d_out, int out_size, void* d_ws, size_t ws_size,
                              hipStream_t stream) {
  const float* s8  = (const float*)d_in[0];
  const float* b8  = (const float*)d_in[1];
  const float* l8  = (const float*)d_in[2];
  const float* s16 = (const float*)d_in[3];
  const float* b16 = (const float*)d_in[4];
  const float* l16 = (const float*)d_in[5];
  const float* s32 = (const float*)d_in[6];
  const float* b32 = (const float*)d_in[7];
  const float* l32 = (const float*)d_in[8];
  const float* dsp = (const float*)d_in[9];
  char* ws = (char*)d_ws;
  unsigned* hist = (unsigned*)(ws + OFF_HIST);
  unsigned* meta = (unsigned*)(ws + OFF_META);
  unsigned long long* cand = (unsigned long long*)(ws + OFF_CAND);
  unsigned* tidx = (unsigned*)(ws + OFF_TIDX);
  float* tconf = (float*)(ws + OFF_TCONF);
  float* box = (float*)(ws + OFF_BOX);
  unsigned long long* vmask = (unsigned long long*)(ws + OFF_VMASK);
  unsigned* keepm = (unsigned*)(ws + OFF_KEEP);
  unsigned long long* supp = (unsigned long long*)(ws + OFF_SUPP);
  float* out = (float*)d_out;

  hipMemsetAsync(ws, 0, OFF_META + 64, stream);  // hist + meta
  k_hist<<<2048, 256, 0, stream>>>(s8, s16, s32, hist);
  k_scan<<<1, 1024, 0, stream>>>(hist, meta);
  k_compact<<<2048, 256, 0, stream>>>(s8, s16, s32, meta, cand);
  k_sort_gather<<<1, 1024, 0, stream>>>(cand, meta, b8, l8, b16, l16, b32, l32,
                                        dsp, tidx, tconf, box, vmask);
  k_supp<<<TOPK, 256, 0, stream>>>(box, supp);
  k_nms<<<1, 64, 0, stream>>>((const unsigned*)supp, (const unsigned*)vmask, keepm);
  k_out<<<8, 256, 0, stream>>>(keepm, tidx, tconf, b8, l8, b16, l16, b32, l32,
                               dsp, out);
}

// Round 3
// 122.259 us; speedup vs baseline: 3.1316x; 1.4317x over previous
//
#include <hip/hip_runtime.h>
#include <stdint.h>
#include <stddef.h>

// Match numpy float32 rounding: forbid fma contraction in all float math below.
#pragma clang fp contract(off)

#define N8   819200u
#define N16  204800u
#define N32  51200u
#define NTOT 1075200u
#define TOPK 2048
#define CAND_MAX 8192
#define NBIN 16384u
#define BINSHIFT 9
#define NMS_THR 0.4f
#define DET_THR 0.5f

// ws byte offsets
#define OFF_HIST   0u        // u32[16384]   64KB
#define OFF_META   65536u    // u32[16]
#define OFF_CAND   65600u    // u64[8192]    64KB
#define OFF_TIDX   131136u   // u32[2048]
#define OFF_TCONF  139328u   // f32[2048]
#define OFF_BOX    147520u   // f32[2048*4] (16B aligned)
#define OFF_KEEP   180544u   // u32[64]
#define OFF_SUPP   180800u   // u64[2048*32] 512KB

__device__ __forceinline__ float load_conf(unsigned a, const float* __restrict__ s8,
                                           const float* __restrict__ s16,
                                           const float* __restrict__ s32) {
  if (a < N8) return s8[a];
  if (a < N8 + N16) return s16[a - N8];
  return s32[a - (N8 + N16)];
}

__device__ __forceinline__ void decode(unsigned a,
    const float* __restrict__ b8, const float* __restrict__ l8,
    const float* __restrict__ b16, const float* __restrict__ l16,
    const float* __restrict__ b32, const float* __restrict__ l32,
    float& cx, float& cy, float& s, const float*& bb, const float*& lm) {
  if (a < N8) {
    unsigned cell = a >> 1;
    cx = (float)((cell % 640u) * 8u); cy = (float)((cell / 640u) * 8u);
    s = 8.f; bb = b8 + (size_t)a * 4; lm = l8 + (size_t)a * 10;
  } else if (a < N8 + N16) {
    unsigned loc = a - N8; unsigned cell = loc >> 1;
    cx = (float)((cell % 320u) * 16u); cy = (float)((cell / 320u) * 16u);
    s = 16.f; bb = b16 + (size_t)loc * 4; lm = l16 + (size_t)loc * 10;
  } else {
    unsigned loc = a - (N8 + N16); unsigned cell = loc >> 1;
    cx = (float)((cell % 160u) * 32u); cy = (float)((cell / 160u) * 32u);
    s = 32.f; bb = b32 + (size_t)loc * 4; lm = l32 + (size_t)loc * 10;
  }
}

// K1: histogram of conf>=0.5 on 14-bit prefix of (bits - bits(0.5))
__global__ void k_hist(const float* __restrict__ s8, const float* __restrict__ s16,
                       const float* __restrict__ s32, unsigned* __restrict__ hist) {
  unsigned i = blockIdx.x * blockDim.x + threadIdx.x;
  unsigned st = gridDim.x * blockDim.x;
  for (unsigned a = i; a < NTOT; a += st) {
    float c = load_conf(a, s8, s16, s32);
    if (c >= DET_THR) {
      unsigned v = (__float_as_uint(c) - 0x3F000000u) >> BINSHIFT;
      if (v > NBIN - 1u) v = NBIN - 1u;
      atomicAdd(&hist[v], 1u);
    }
  }
}

// K2: find cutoff prefix (smallest p with suffix-count >= TOPK); single WG
__global__ void __launch_bounds__(1024) k_scan(const unsigned* __restrict__ hist,
                                               unsigned* __restrict__ meta) {
  __shared__ unsigned suf[1024];
  int t = threadIdx.x;
  const unsigned* hp = hist + (size_t)t * 16;
  unsigned s = 0;
  for (int b = 0; b < 16; b++) s += hp[b];
  suf[t] = s;
  __syncthreads();
  for (int d = 1; d < 1024; d <<= 1) {
    unsigned v = (t + d < 1024) ? suf[t + d] : 0u;
    __syncthreads();
    suf[t] += v;
    __syncthreads();
  }
  unsigned total = suf[0];
  unsigned mine = suf[t];
  unsigned nxt = (t < 1023) ? suf[t + 1] : 0u;
  if (total < (unsigned)TOPK) {
    if (t == 0) { meta[0] = 0u; meta[2] = total; }
    return;
  }
  if (mine >= (unsigned)TOPK && nxt < (unsigned)TOPK) {
    unsigned run = nxt, cut = (unsigned)t * 16u;
    for (int b = 15; b >= 0; b--) {
      run += hp[b];
      if (run >= (unsigned)TOPK) { cut = (unsigned)t * 16u + (unsigned)b; break; }
    }
    meta[0] = cut; meta[2] = total;
  }
}

// K3: compact candidates (>= cutoff prefix) as 64-bit sort keys
__global__ void k_compact(const float* __restrict__ s8, const float* __restrict__ s16,
                          const float* __restrict__ s32, unsigned* __restrict__ meta,
                          unsigned long long* __restrict__ cand) {
  unsigned cut = meta[0];
  unsigned i = blockIdx.x * blockDim.x + threadIdx.x;
  unsigned st = gridDim.x * blockDim.x;
  for (unsigned a = i; a < NTOT; a += st) {
    float c = load_conf(a, s8, s16, s32);
    if (c >= DET_THR) {
      unsigned b = __float_as_uint(c);
      unsigned v = (b - 0x3F000000u) >> BINSHIFT;
      if (v >= cut) {
        unsigned pos = atomicAdd(&meta[3], 1u);
        if (pos < (unsigned)CAND_MAX)
          cand[pos] = ((unsigned long long)b << 32) |
                      (unsigned long long)(0xFFFFFFFFu - a);
      }
    }
  }
}

// K4: rank-and-scatter (replaces bitonic sort). Keys are unique, so
// rank(x) = #{y : y > x} is a permutation. One wave per candidate: 64 lanes
// stride the key array (L2-resident), 6-step shfl reduce, lane 0 decodes the
// box and scatters idx/conf/box to its rank position.
__global__ void __launch_bounds__(256) k_rank(
    const unsigned long long* __restrict__ cand, const unsigned* __restrict__ meta,
    const float* __restrict__ b8, const float* __restrict__ l8,
    const float* __restrict__ b16, const float* __restrict__ l16,
    const float* __restrict__ b32, const float* __restrict__ l32,
    const float* __restrict__ dsp,
    unsigned* __restrict__ tidx, float* __restrict__ tconf, float* __restrict__ box) {
  unsigned count = meta[3];
  if (count > (unsigned)CAND_MAX) count = (unsigned)CAND_MAX;
  unsigned wave = blockIdx.x * 4u + (threadIdx.x >> 6);
  unsigned lane = threadIdx.x & 63u;
  if (wave >= count) return;
  unsigned long long my = cand[wave];
  unsigned cnt = 0;
  for (unsigned i = lane; i < count; i += 64u)
    cnt += (cand[i] > my) ? 1u : 0u;
  for (int d = 32; d > 0; d >>= 1) cnt += __shfl_down(cnt, d);
  if (lane == 0 && cnt < (unsigned)TOPK) {
    unsigned r = cnt;
    unsigned a = 0xFFFFFFFFu - (unsigned)(my & 0xFFFFFFFFull);
    float conf = __uint_as_float((unsigned)(my >> 32));
    float cx, cy, s; const float* bb; const float* lm;
    decode(a, b8, l8, b16, l16, b32, l32, cx, cy, s, bb, lm);
    float ds = dsp[0];
    float b0 = bb[0] * s, b1 = bb[1] * s, b2 = bb[2] * s, b3 = bb[3] * s;
    box[r * 4 + 0] = (cx - b0) / ds;
    box[r * 4 + 1] = (cy - b1) / ds;
    box[r * 4 + 2] = (cx + b2) / ds;
    box[r * 4 + 3] = (cy + b3) / ds;
    tidx[r] = a; tconf[r] = conf;
  }
}

// K5: bit-packed suppression matrix: bit[i][j] = (iou > thr) && (j > i)
// Rows/cols >= count contain stale data; harmless (their keep bits are never
// set, and NaN/garbage IoU compares yield false).
__global__ void __launch_bounds__(256) k_supp(const float* __restrict__ box,
                                              unsigned long long* __restrict__ supp) {
  int i = blockIdx.x;
  const float4 bi = ((const float4*)box)[i];
  float ai = fmaxf(bi.z - bi.x, 0.f) * fmaxf(bi.w - bi.y, 0.f);
  int tid = threadIdx.x;
  int lane = tid & 63, wv = tid >> 6;
  for (int base = 0; base < TOPK; base += 256) {
    int j = base + tid;
    const float4 bj = ((const float4*)box)[j];
    float aj = fmaxf(bj.z - bj.x, 0.f) * fmaxf(bj.w - bj.y, 0.f);
    float ltx = fmaxf(bi.x, bj.x), lty = fmaxf(bi.y, bj.y);
    float rbx = fminf(bi.z, bj.z), rby = fminf(bi.w, bj.w);
    float w = fmaxf(rbx - ltx, 0.f), h = fmaxf(rby - lty, 0.f);
    float inter = w * h;
    float iou = inter / (ai + aj - inter + 1e-9f);
    bool pred = (iou > NMS_THR) && (j > i);
    unsigned long long word = __ballot(pred);
    if (lane == 0) supp[(size_t)i * 32 + (base >> 6) + wv] = word;
  }
}

// K6: greedy NMS via chunked closure + bulk apply.
// Valid mask computed arithmetically from count (all candidates have
// conf >= DET_THR by construction; rows >= min(count,TOPK) are invalid).
__global__ void __launch_bounds__(64) k_nms(const unsigned* __restrict__ supp32,
                                            const unsigned* __restrict__ meta,
                                            unsigned* __restrict__ keepmask) {
  int lane = threadIdx.x;
  unsigned count = meta[3];
  if (count > (unsigned)TOPK) count = (unsigned)TOPK;
  unsigned lo = (unsigned)lane * 32u;
  unsigned kw = (count >= lo + 32u) ? 0xFFFFFFFFu
              : (count <= lo ? 0u : ((1u << (count - lo)) - 1u));
  const unsigned* sp = supp32 + lane;
  unsigned Ta[32], Tb[32];
#define LOADT(BUF, C)                                                         \
  _Pragma("unroll") for (int k = 0; k < 32; k++)                              \
      BUF[k] = sp[((size_t)((C) * 32 + k)) * 64];
#define PROCESS(BUF, C)                                                       \
  {                                                                           \
    unsigned w = __builtin_amdgcn_readlane(kw, (C));                          \
    _Pragma("unroll") for (int k = 0; k < 32; k++) {                          \
      unsigned mk = 0u - ((w >> k) & 1u);                                     \
      w &= ~(BUF[k] & mk);                                                    \
    }                                                                         \
    w = __builtin_amdgcn_readlane(w, (C));                                    \
    unsigned acc = 0u;                                                        \
    _Pragma("unroll") for (int k = 0; k < 32; k++) {                          \
      unsigned mk = 0u - ((w >> k) & 1u);                                     \
      acc |= BUF[k] & mk;                                                     \
    }                                                                         \
    kw &= ~acc;                                                               \
  }
  LOADT(Ta, 0)
#pragma unroll 1
  for (int c = 0; c < 64; c += 2) {
    LOADT(Tb, c + 1)
    PROCESS(Ta, c)
    if (c + 2 < 64) LOADT(Ta, c + 2)
    PROCESS(Tb, c + 1)
  }
#undef LOADT
#undef PROCESS
  keepmask[lane] = kw;
}

// K7: decode + write all 2048x15 outputs (suppressed rows zeroed)
__global__ void __launch_bounds__(256) k_out(
    const unsigned* __restrict__ keepmask,
    const unsigned* __restrict__ tidx, const float* __restrict__ tconf,
    const float* __restrict__ b8, const float* __restrict__ l8,
    const float* __restrict__ b16, const float* __restrict__ l16,
    const float* __restrict__ b32, const float* __restrict__ l32,
    const float* __restrict__ dsp, float* __restrict__ out) {
  int r = blockIdx.x * 256 + threadIdx.x;
  if (r >= TOPK) return;
  bool kept = (keepmask[r >> 5] >> (r & 31)) & 1u;
  float o[15];
  if (kept) {
    unsigned a = tidx[r];
    float cx, cy, s; const float* bb; const float* lm;
    decode(a, b8, l8, b16, l16, b32, l32, cx, cy, s, bb, lm);
    float ds = dsp[0];
    o[0] = tconf[r];
    float b0 = bb[0] * s, b1 = bb[1] * s, b2 = bb[2] * s, b3 = bb[3] * s;
    o[1] = (cx - b0) / ds;
    o[2] = (cy - b1) / ds;
    o[3] = (cx + b2) / ds;
    o[4] = (cy + b3) / ds;
    for (int p = 0; p < 5; p++) {
      float lx = lm[2 * p] * s, ly = lm[2 * p + 1] * s;
      o[5 + 2 * p] = (cx + lx) / ds;
      o[6 + 2 * p] = (cy + ly) / ds;
    }
  } else {
    for (int c = 0; c < 15; c++) o[c] = 0.f;
  }
  for (int c = 0; c < 15; c++) out[(size_t)r * 15 + c] = o[c];
}

extern "C" void kernel_launch(void* const* d_in, const int* in_sizes, int n_in,
                              void* d_out, int out_size, void* d_ws, size_t ws_size,
                              hipStream_t stream) {
  const float* s8  = (const float*)d_in[0];
  const float* b8  = (const float*)d_in[1];
  const float* l8  = (const float*)d_in[2];
  const float* s16 = (const float*)d_in[3];
  const float* b16 = (const float*)d_in[4];
  const float* l16 = (const float*)d_in[5];
  const float* s32 = (const float*)d_in[6];
  const float* b32 = (const float*)d_in[7];
  const float* l32 = (const float*)d_in[8];
  const float* dsp = (const float*)d_in[9];
  char* ws = (char*)d_ws;
  unsigned* hist = (unsigned*)(ws + OFF_HIST);
  unsigned* meta = (unsigned*)(ws + OFF_META);
  unsigned long long* cand = (unsigned long long*)(ws + OFF_CAND);
  unsigned* tidx = (unsigned*)(ws + OFF_TIDX);
  float* tconf = (float*)(ws + OFF_TCONF);
  float* box = (float*)(ws + OFF_BOX);
  unsigned* keepm = (unsigned*)(ws + OFF_KEEP);
  unsigned long long* supp = (unsigned long long*)(ws + OFF_SUPP);
  float* out = (float*)d_out;

  hipMemsetAsync(ws, 0, OFF_META + 64, stream);  // hist + meta
  k_hist<<<2048, 256, 0, stream>>>(s8, s16, s32, hist);
  k_scan<<<1, 1024, 0, stream>>>(hist, meta);
  k_compact<<<2048, 256, 0, stream>>>(s8, s16, s32, meta, cand);
  k_rank<<<CAND_MAX / 4, 256, 0, stream>>>(cand, meta, b8, l8, b16, l16, b32, l32,
                                           dsp, tidx, tconf, box);
  k_supp<<<TOPK, 256, 0, stream>>>(box, supp);
  k_nms<<<1, 64, 0, stream>>>((const unsigned*)supp, meta, keepm);
  k_out<<<8, 256, 0, stream>>>(keepm, tidx, tconf, b8, l8, b16, l16, b32, l32,
                               dsp, out);
}

// Round 4
// 119.903 us; speedup vs baseline: 3.1931x; 1.0196x over previous
//
#include <hip/hip_runtime.h>
#include <stdint.h>
#include <stddef.h>

// Match numpy float32 rounding: forbid fma contraction in all float math below.
#pragma clang fp contract(off)

#define N8   819200u
#define N16  204800u
#define N32  51200u
#define NTOT 1075200u
#define TOPK 2048
#define CAND_MAX 8192
#define NBIN 16384u
#define BINSHIFT 9
#define NMS_THR 0.4f
#define DET_THR 0.5f

// ws byte offsets
#define OFF_HIST   0u        // u32[16384]   64KB
#define OFF_META   65536u    // u32[16]
#define OFF_CAND   65600u    // u64[8192]    64KB
#define OFF_TIDX   131136u   // u32[2048]
#define OFF_TCONF  139328u   // f32[2048]
#define OFF_BOX    147520u   // f32[2048*4] (16B aligned)
#define OFF_KEEP   180544u   // u32[64]
#define OFF_DIAG   180800u   // u32[2048]    8KB
#define OFF_SUPP   188992u   // u64[2048*32] 512KB

__device__ __forceinline__ float load_conf(unsigned a, const float* __restrict__ s8,
                                           const float* __restrict__ s16,
                                           const float* __restrict__ s32) {
  if (a < N8) return s8[a];
  if (a < N8 + N16) return s16[a - N8];
  return s32[a - (N8 + N16)];
}

__device__ __forceinline__ void decode(unsigned a,
    const float* __restrict__ b8, const float* __restrict__ l8,
    const float* __restrict__ b16, const float* __restrict__ l16,
    const float* __restrict__ b32, const float* __restrict__ l32,
    float& cx, float& cy, float& s, const float*& bb, const float*& lm) {
  if (a < N8) {
    unsigned cell = a >> 1;
    cx = (float)((cell % 640u) * 8u); cy = (float)((cell / 640u) * 8u);
    s = 8.f; bb = b8 + (size_t)a * 4; lm = l8 + (size_t)a * 10;
  } else if (a < N8 + N16) {
    unsigned loc = a - N8; unsigned cell = loc >> 1;
    cx = (float)((cell % 320u) * 16u); cy = (float)((cell / 320u) * 16u);
    s = 16.f; bb = b16 + (size_t)loc * 4; lm = l16 + (size_t)loc * 10;
  } else {
    unsigned loc = a - (N8 + N16); unsigned cell = loc >> 1;
    cx = (float)((cell % 160u) * 32u); cy = (float)((cell / 160u) * 32u);
    s = 32.f; bb = b32 + (size_t)loc * 4; lm = l32 + (size_t)loc * 10;
  }
}

// K1: histogram of conf>=0.5 on 14-bit prefix of (bits - bits(0.5))
__global__ void k_hist(const float* __restrict__ s8, const float* __restrict__ s16,
                       const float* __restrict__ s32, unsigned* __restrict__ hist) {
  unsigned i = blockIdx.x * blockDim.x + threadIdx.x;
  unsigned st = gridDim.x * blockDim.x;
  for (unsigned a = i; a < NTOT; a += st) {
    float c = load_conf(a, s8, s16, s32);
    if (c >= DET_THR) {
      unsigned v = (__float_as_uint(c) - 0x3F000000u) >> BINSHIFT;
      if (v > NBIN - 1u) v = NBIN - 1u;
      atomicAdd(&hist[v], 1u);
    }
  }
}

// K2: find cutoff prefix (smallest p with suffix-count >= TOPK); single WG
__global__ void __launch_bounds__(1024) k_scan(const unsigned* __restrict__ hist,
                                               unsigned* __restrict__ meta) {
  __shared__ unsigned suf[1024];
  int t = threadIdx.x;
  const unsigned* hp = hist + (size_t)t * 16;
  unsigned s = 0;
  for (int b = 0; b < 16; b++) s += hp[b];
  suf[t] = s;
  __syncthreads();
  for (int d = 1; d < 1024; d <<= 1) {
    unsigned v = (t + d < 1024) ? suf[t + d] : 0u;
    __syncthreads();
    suf[t] += v;
    __syncthreads();
  }
  unsigned total = suf[0];
  unsigned mine = suf[t];
  unsigned nxt = (t < 1023) ? suf[t + 1] : 0u;
  if (total < (unsigned)TOPK) {
    if (t == 0) { meta[0] = 0u; meta[2] = total; }
    return;
  }
  if (mine >= (unsigned)TOPK && nxt < (unsigned)TOPK) {
    unsigned run = nxt, cut = (unsigned)t * 16u;
    for (int b = 15; b >= 0; b--) {
      run += hp[b];
      if (run >= (unsigned)TOPK) { cut = (unsigned)t * 16u + (unsigned)b; break; }
    }
    meta[0] = cut; meta[2] = total;
  }
}

// K3: compact candidates (>= cutoff prefix) as 64-bit sort keys
__global__ void k_compact(const float* __restrict__ s8, const float* __restrict__ s16,
                          const float* __restrict__ s32, unsigned* __restrict__ meta,
                          unsigned long long* __restrict__ cand) {
  unsigned cut = meta[0];
  unsigned i = blockIdx.x * blockDim.x + threadIdx.x;
  unsigned st = gridDim.x * blockDim.x;
  for (unsigned a = i; a < NTOT; a += st) {
    float c = load_conf(a, s8, s16, s32);
    if (c >= DET_THR) {
      unsigned b = __float_as_uint(c);
      unsigned v = (b - 0x3F000000u) >> BINSHIFT;
      if (v >= cut) {
        unsigned pos = atomicAdd(&meta[3], 1u);
        if (pos < (unsigned)CAND_MAX)
          cand[pos] = ((unsigned long long)b << 32) |
                      (unsigned long long)(0xFFFFFFFFu - a);
      }
    }
  }
}

// K4: rank-and-scatter. Keys unique -> rank(x)=#{y>x} is a permutation.
__global__ void __launch_bounds__(256) k_rank(
    const unsigned long long* __restrict__ cand, const unsigned* __restrict__ meta,
    const float* __restrict__ b8, const float* __restrict__ l8,
    const float* __restrict__ b16, const float* __restrict__ l16,
    const float* __restrict__ b32, const float* __restrict__ l32,
    const float* __restrict__ dsp,
    unsigned* __restrict__ tidx, float* __restrict__ tconf, float* __restrict__ box) {
  unsigned count = meta[3];
  if (count > (unsigned)CAND_MAX) count = (unsigned)CAND_MAX;
  unsigned wave = blockIdx.x * 4u + (threadIdx.x >> 6);
  unsigned lane = threadIdx.x & 63u;
  if (wave >= count) return;
  unsigned long long my = cand[wave];
  unsigned cnt = 0;
  for (unsigned i = lane; i < count; i += 64u)
    cnt += (cand[i] > my) ? 1u : 0u;
  for (int d = 32; d > 0; d >>= 1) cnt += __shfl_down(cnt, d);
  if (lane == 0 && cnt < (unsigned)TOPK) {
    unsigned r = cnt;
    unsigned a = 0xFFFFFFFFu - (unsigned)(my & 0xFFFFFFFFull);
    float conf = __uint_as_float((unsigned)(my >> 32));
    float cx, cy, s; const float* bb; const float* lm;
    decode(a, b8, l8, b16, l16, b32, l32, cx, cy, s, bb, lm);
    float ds = dsp[0];
    float b0 = bb[0] * s, b1 = bb[1] * s, b2 = bb[2] * s, b3 = bb[3] * s;
    box[r * 4 + 0] = (cx - b0) / ds;
    box[r * 4 + 1] = (cy - b1) / ds;
    box[r * 4 + 2] = (cx + b2) / ds;
    box[r * 4 + 3] = (cy + b3) / ds;
    tidx[r] = a; tconf[r] = conf;
  }
}

// K5: bit-packed suppression matrix: bit[i][j] = (iou > thr) && (j > i).
// Also emits diag32[i] = the u32 diagonal word (word i>>5) of row i, so the
// NMS closure can run on the scalar unit.
__global__ void __launch_bounds__(256) k_supp(const float* __restrict__ box,
                                              unsigned long long* __restrict__ supp,
                                              unsigned* __restrict__ diag32) {
  int i = blockIdx.x;
  const float4 bi = ((const float4*)box)[i];
  float ai = fmaxf(bi.z - bi.x, 0.f) * fmaxf(bi.w - bi.y, 0.f);
  int tid = threadIdx.x;
  int lane = tid & 63, wv = tid >> 6;
  for (int base = 0; base < TOPK; base += 256) {
    int j = base + tid;
    const float4 bj = ((const float4*)box)[j];
    float aj = fmaxf(bj.z - bj.x, 0.f) * fmaxf(bj.w - bj.y, 0.f);
    float ltx = fmaxf(bi.x, bj.x), lty = fmaxf(bi.y, bj.y);
    float rbx = fminf(bi.z, bj.z), rby = fminf(bi.w, bj.w);
    float w = fmaxf(rbx - ltx, 0.f), h = fmaxf(rby - lty, 0.f);
    float inter = w * h;
    float iou = inter / (ai + aj - inter + 1e-9f);
    bool pred = (iou > NMS_THR) && (j > i);
    unsigned long long word = __ballot(pred);
    int w64 = (base >> 6) + wv;
    if (lane == 0) {
      supp[(size_t)i * 32 + w64] = word;
      if (w64 == (i >> 6))
        diag32[i] = (unsigned)(word >> (((i >> 5) & 1) * 32));
    }
  }
}

// K6: greedy NMS, single wave. Scalar-unit closure over diag32 (uniform
// s_loads, double-buffered), v_and_or bulk apply, depth-4 vector prefetch.
// Lane l owns keep word covering j in [32l, 32l+32).
__global__ void __launch_bounds__(64) k_nms(const unsigned* __restrict__ supp32,
                                            const unsigned* __restrict__ diag32,
                                            const unsigned* __restrict__ meta,
                                            unsigned* __restrict__ keepmask) {
  int lane = threadIdx.x;
  unsigned count = meta[3];
  if (count > (unsigned)TOPK) count = (unsigned)TOPK;
  unsigned lo = (unsigned)lane * 32u;
  unsigned kw = (count >= lo + 32u) ? 0xFFFFFFFFu
              : (count <= lo ? 0u : ((1u << (count - lo)) - 1u));
  const unsigned* sp = supp32 + lane;
  unsigned T0[32], T1[32], T2[32], T3[32];
  unsigned dga[32], dgb[32];

#define LOADT(BUF, C)                                                         \
  _Pragma("unroll") for (int k = 0; k < 32; k++)                              \
      BUF[k] = sp[((size_t)(unsigned)((C) * 32 + k)) * 64];
#define LOADD(DBUF, C)                                                        \
  _Pragma("unroll") for (int k = 0; k < 32; k++)                              \
      DBUF[k] = diag32[(unsigned)((C) * 32 + k)];

  LOADT(T0, 0) LOADT(T1, 1) LOADT(T2, 2) LOADT(T3, 3)
  LOADD(dga, 0)

#define STEP(BUF, DCUR, DNXT, C)                                              \
  {                                                                           \
    unsigned w = __builtin_amdgcn_readlane(kw, (C));                          \
    _Pragma("unroll") for (int k = 0; k < 32; k++) {                          \
      unsigned t = ((w >> k) & 1u) ? DCUR[k] : 0u;                            \
      w &= ~t;                                                                \
    }                                                                         \
    if ((C) + 1 < 64) { LOADD(DNXT, (C) + 1) }                                \
    unsigned acc = 0u;                                                        \
    _Pragma("unroll") for (int k = 0; k < 32; k++) {                          \
      unsigned mk = (unsigned)((int)(w << (31 - k)) >> 31);                   \
      acc |= BUF[k] & mk;                                                     \
    }                                                                         \
    kw &= ~acc;                                                               \
    if ((C) + 4 < 64) { LOADT(BUF, (C) + 4) }                                 \
  }

#pragma unroll 1
  for (int c = 0; c < 64; c += 8) {
    STEP(T0, dga, dgb, c + 0)
    STEP(T1, dgb, dga, c + 1)
    STEP(T2, dga, dgb, c + 2)
    STEP(T3, dgb, dga, c + 3)
    STEP(T0, dga, dgb, c + 4)
    STEP(T1, dgb, dga, c + 5)
    STEP(T2, dga, dgb, c + 6)
    STEP(T3, dgb, dga, c + 7)
  }
#undef LOADT
#undef LOADD
#undef STEP
  keepmask[lane] = kw;
}

// K7: decode + write all 2048x15 outputs (suppressed rows zeroed)
__global__ void __launch_bounds__(256) k_out(
    const unsigned* __restrict__ keepmask,
    const unsigned* __restrict__ tidx, const float* __restrict__ tconf,
    const float* __restrict__ b8, const float* __restrict__ l8,
    const float* __restrict__ b16, const float* __restrict__ l16,
    const float* __restrict__ b32, const float* __restrict__ l32,
    const float* __restrict__ dsp, float* __restrict__ out) {
  int r = blockIdx.x * 256 + threadIdx.x;
  if (r >= TOPK) return;
  bool kept = (keepmask[r >> 5] >> (r & 31)) & 1u;
  float o[15];
  if (kept) {
    unsigned a = tidx[r];
    float cx, cy, s; const float* bb; const float* lm;
    decode(a, b8, l8, b16, l16, b32, l32, cx, cy, s, bb, lm);
    float ds = dsp[0];
    o[0] = tconf[r];
    float b0 = bb[0] * s, b1 = bb[1] * s, b2 = bb[2] * s, b3 = bb[3] * s;
    o[1] = (cx - b0) / ds;
    o[2] = (cy - b1) / ds;
    o[3] = (cx + b2) / ds;
    o[4] = (cy + b3) / ds;
    for (int p = 0; p < 5; p++) {
      float lx = lm[2 * p] * s, ly = lm[2 * p + 1] * s;
      o[5 + 2 * p] = (cx + lx) / ds;
      o[6 + 2 * p] = (cy + ly) / ds;
    }
  } else {
    for (int c = 0; c < 15; c++) o[c] = 0.f;
  }
  for (int c = 0; c < 15; c++) out[(size_t)r * 15 + c] = o[c];
}

extern "C" void kernel_launch(void* const* d_in, const int* in_sizes, int n_in,
                              void* d_out, int out_size, void* d_ws, size_t ws_size,
                              hipStream_t stream) {
  const float* s8  = (const float*)d_in[0];
  const float* b8  = (const float*)d_in[1];
  const float* l8  = (const float*)d_in[2];
  const float* s16 = (const float*)d_in[3];
  const float* b16 = (const float*)d_in[4];
  const float* l16 = (const float*)d_in[5];
  const float* s32 = (const float*)d_in[6];
  const float* b32 = (const float*)d_in[7];
  const float* l32 = (const float*)d_in[8];
  const float* dsp = (const float*)d_in[9];
  char* ws = (char*)d_ws;
  unsigned* hist = (unsigned*)(ws + OFF_HIST);
  unsigned* meta = (unsigned*)(ws + OFF_META);
  unsigned long long* cand = (unsigned long long*)(ws + OFF_CAND);
  unsigned* tidx = (unsigned*)(ws + OFF_TIDX);
  float* tconf = (float*)(ws + OFF_TCONF);
  float* box = (float*)(ws + OFF_BOX);
  unsigned* keepm = (unsigned*)(ws + OFF_KEEP);
  unsigned* diag = (unsigned*)(ws + OFF_DIAG);
  unsigned long long* supp = (unsigned long long*)(ws + OFF_SUPP);
  float* out = (float*)d_out;

  hipMemsetAsync(ws, 0, OFF_META + 64, stream);  // hist + meta
  k_hist<<<2048, 256, 0, stream>>>(s8, s16, s32, hist);
  k_scan<<<1, 1024, 0, stream>>>(hist, meta);
  k_compact<<<2048, 256, 0, stream>>>(s8, s16, s32, meta, cand);
  k_rank<<<CAND_MAX / 4, 256, 0, stream>>>(cand, meta, b8, l8, b16, l16, b32, l32,
                                           dsp, tidx, tconf, box);
  k_supp<<<TOPK, 256, 0, stream>>>(box, supp, diag);
  k_nms<<<1, 64, 0, stream>>>((const unsigned*)supp, diag, meta, keepm);
  k_out<<<8, 256, 0, stream>>>(keepm, tidx, tconf, b8, l8, b16, l16, b32, l32,
                               dsp, out);
}